// Round 9
// baseline (232.966 us; speedup 1.0000x reference)
//
#include <hip/hip_runtime.h>
#include <stdint.h>

#define BB 32
#define SS 512
#define HH 256
#define MM (BB*SS)     // 16384 rows
#define MAXMEL 2048

typedef _Float16 f16;
typedef _Float16 f16x4 __attribute__((ext_vector_type(4)));
typedef _Float16 f16x8 __attribute__((ext_vector_type(8)));
typedef float    f32x16 __attribute__((ext_vector_type(16)));

#define BAR()  asm volatile("s_barrier" ::: "memory")
#define VMW9() asm volatile("s_waitcnt vmcnt(9)" ::: "memory")
#define VMW0() asm volatile("s_waitcnt vmcnt(0)" ::: "memory")

// Xq layout: [pane 32][row MM][8 f16], pane = chan>>3. 16B per row per pane.
__device__ __forceinline__ size_t xoff8(int pane, int row) {
  return ((size_t)pane * MM + row) * 8;
}

// LDS map (bytes): B0 @0 (24576 = [p2][tap3][g2][col128][16B]), B1 @24576,
// A0 @49152 (12288 = [p2][g2][lr192][16B], + 64B zero tail @61440), A1 @61504.
#define AOFF  49152
#define ABUF  12352
#define AZ    61440         // A0 zero tail; A1's lands at 73792
#define BBUF  24576
#define LDSSZ 73856
#define WSZP ((size_t)393216)   // packed weight f16 elems per conv (both planes)

// ---------------- conv1d (K=3 SAME, 256->256), split-f16 MFMA ----------------
// Block 128x128, 4 waves (2x2), wave 64x64 as 2x2 frags of 32x32x16.
// 16 steps of (16 chans x 3 taps). Double-buffered LDS, counted vmcnt(9).
// 3-product split: Ahi*Bhi + Ahi*Blo + Alo*Bhi (~f32 accuracy).
// RAW=0: bz=predictor (fused pair). RAW=1: bz=K-half, raw f32 partials.
// g-major LDS: fragment reads are lane-contiguous 16B -> bank-conflict-free.
template<int NS, int RAW>
__global__ __launch_bounds__(256) void conv16(
    const f16* __restrict__ X0h, const f16* __restrict__ X0l,
    const f16* __restrict__ X1h_, const f16* __restrict__ X1l_,
    const f16* __restrict__ W0, const f16* __restrict__ W1,   // packed
    const float* __restrict__ bias0, const float* __restrict__ bias1,
    f16* __restrict__ Y0h, f16* __restrict__ Y0l,
    f16* __restrict__ Y1h, f16* __restrict__ Y1l,
    float* __restrict__ Craw)
{
  __shared__ __align__(16) unsigned char smem[LDSSZ];
  const int tid = threadIdx.x;
  const int lane = tid & 63, wid = tid >> 6;
  const int bm = blockIdx.x, bn = blockIdx.y, bz = blockIdx.z;
  const int l31 = lane & 31, half = lane >> 5;
  const int wr = wid >> 1, wc = wid & 1;

  const int s0 = RAW ? bz * 8 : 0;
  const f16* Xh = (RAW || bz == 0) ? X0h : X1h_;
  const f16* Xl = (RAW || bz == 0) ? X0l : X1l_;
  const f16* Wp = (RAW || bz == 0) ? W0 : W1;

  // ---- stage descriptors: 9 DMA per thread (A 12 + B 24 = 36 per block) ----
  const f16* sb[9]; int sdst[9]; int sdb[9]; size_t sstr[9];
  #pragma unroll
  for (int i = 0; i < 9; ++i) {
    int j = wid * 9 + i;
    if (j < 12) {                 // A: [p][g][3 segs of 64 rows]
      int p = j / 6, rem = j % 6, g = rem / 3, seg = rem % 3;
      int lr = seg * 64 + lane;
      int row = bm * 128 - 32 + lr;          // per-lane clamped source row;
      row = row < 0 ? 0 : (row >= MM ? MM - 1 : row);   // clamped slots only
      sb[i]   = (p ? Xl : Xh) + ((size_t)g * MM + row) * 8;  // feed AZ-frags
      sstr[i] = (size_t)MM * 16;             // 2 panes per step
      sdst[i] = AOFF + p * 6144 + g * 3072 + lr * 16;
      sdb[i]  = ABUF;
    } else {                      // B: [p][tap][g][2 x 64 cols]
      int jj = j - 12;            // 0..23
      int p = jj / 12, rest = jj % 12;
      int tap = rest >> 2, q = rest & 3;
      int g = q >> 1, h2 = q & 1;
      sb[i]   = Wp + ((((((size_t)(bn * 16) * 2 + p) * 3 + tap) * 2 + g) * 128)
                      + h2 * 64 + lane) * 8;
      sstr[i] = 12288;
      sdst[i] = p * 12288 + tap * 4096 + g * 2048 + h2 * 1024 + lane * 16;
      sdb[i]  = BBUF;
    }
  }

  // ---- fragment read addresses (lane-contiguous: +l31*16) ----
  int a_addr[3][2][2];            // [tap][mi][p]
  #pragma unroll
  for (int tap = 0; tap < 3; ++tap)
    #pragma unroll
    for (int mi = 0; mi < 2; ++mi) {
      int row_l = wr * 64 + mi * 32 + l31;
      int sseq = (bm & 3) * 128 + row_l + tap - 1;
      bool valid = (unsigned)sseq < 512u;
      int lr = row_l + tap + 31;
      #pragma unroll
      for (int p = 0; p < 2; ++p)
        a_addr[tap][mi][p] = valid ? (AOFF + p * 6144 + half * 3072 + lr * 16)
                                   : AZ;
    }
  int b_base[2];
  #pragma unroll
  for (int n = 0; n < 2; ++n)
    b_base[n] = half * 2048 + (wc * 64 + n * 32 + l31) * 16;

  f32x16 acc[2][2];
  #pragma unroll
  for (int mi = 0; mi < 2; ++mi)
    #pragma unroll
    for (int ni = 0; ni < 2; ++ni) acc[mi][ni] = (f32x16)0.f;

  auto STAGE = [&](int buf, int step) {
    #pragma unroll
    for (int i = 0; i < 9; ++i)
      __builtin_amdgcn_global_load_lds(
        (const __attribute__((address_space(1))) void*)(sb[i] + (size_t)step * sstr[i]),
        (__attribute__((address_space(3))) void*)(smem + sdst[i] + buf * sdb[i]),
        16, 0, 0);
  };

  auto COMP = [&](int buf) {
    #pragma unroll
    for (int tap = 0; tap < 3; ++tap) {
      f16x8 av[2][2], bv[2][2];        // [p][mi], [p][ni]
      #pragma unroll
      for (int p = 0; p < 2; ++p)
        #pragma unroll
        for (int q = 0; q < 2; ++q) {
          av[p][q] = *(const f16x8*)(smem + (a_addr[tap][q][p] + buf * ABUF));
          bv[p][q] = *(const f16x8*)(smem + (buf * BBUF + p * 12288 + tap * 4096 + b_base[q]));
        }
      #pragma unroll
      for (int mi = 0; mi < 2; ++mi)
        #pragma unroll
        for (int ni = 0; ni < 2; ++ni) {
          acc[mi][ni] = __builtin_amdgcn_mfma_f32_32x32x16_f16(av[0][mi], bv[0][ni], acc[mi][ni], 0, 0, 0);
          acc[mi][ni] = __builtin_amdgcn_mfma_f32_32x32x16_f16(av[0][mi], bv[1][ni], acc[mi][ni], 0, 0, 0);
          acc[mi][ni] = __builtin_amdgcn_mfma_f32_32x32x16_f16(av[1][mi], bv[0][ni], acc[mi][ni], 0, 0, 0);
        }
    }
  };

  if (tid < 4) {
    *(float4*)(smem + AZ + tid * 16) = make_float4(0.f, 0.f, 0.f, 0.f);
    *(float4*)(smem + AZ + ABUF + tid * 16) = make_float4(0.f, 0.f, 0.f, 0.f);
  }
  STAGE(0, s0); STAGE(1, s0 + 1);
  __syncthreads();                 // drains vmcnt; zeros + first 2 steps visible

  #pragma unroll
  for (int i = 0; i < NS; ++i) {
    COMP(i & 1);
    BAR();                         // all waves done reading buf i&1
    if (i < NS - 2)       { STAGE(i & 1, s0 + i + 2); VMW9(); }
    else if (i == NS - 2) { VMW0(); }
    BAR();                         // step i+1 landed everywhere
  }

  // epilogue. C/D layout: col=lane&31, row=(reg&3)+8*(reg>>2)+4*(lane>>5)
  if constexpr (RAW) {
    float* C = Craw + (size_t)bz * MM * 256;
    #pragma unroll
    for (int mi = 0; mi < 2; ++mi)
      #pragma unroll
      for (int ni = 0; ni < 2; ++ni) {
        int colg = bn * 128 + wc * 64 + ni * 32 + l31;
        #pragma unroll
        for (int r = 0; r < 16; ++r) {
          int rowl = (r & 3) + 8 * (r >> 2) + 4 * half;
          size_t rowg = (size_t)bm * 128 + wr * 64 + mi * 32 + rowl;
          C[rowg * 256 + colg] = acc[mi][ni][r];
        }
      }
  } else {
    const float* bias = bz ? bias1 : bias0;
    f16* Yh = bz ? Y1h : Y0h;
    f16* Yl = bz ? Y1l : Y0l;
    #pragma unroll
    for (int mi = 0; mi < 2; ++mi)
      #pragma unroll
      for (int ni = 0; ni < 2; ++ni) {
        int colg = bn * 128 + wc * 64 + ni * 32 + l31;
        float bvs = bias[colg];
        size_t cbase = (size_t)(colg >> 3) * MM * 8 + (colg & 7);
        #pragma unroll
        for (int r = 0; r < 16; ++r) {
          int rowl = (r & 3) + 8 * (r >> 2) + 4 * half;
          int rowg = bm * 128 + wr * 64 + mi * 32 + rowl;
          float v = fmaxf(acc[mi][ni][r] + bvs, 0.f);
          f16 h = (f16)v;
          f16 l = (f16)(v - (float)h);
          size_t o = cbase + (size_t)rowg * 8;
          Yh[o] = h;
          Yl[o] = l;
        }
      }
  }
}

// ---------------- weight pack+split, all 6 weights in one launch ----------------
// packed per conv, 16B unit id = ((((bn*16+s)*2+p)*3+tap)*2+g)*128 + col
__global__ __launch_bounds__(256) void wsplit6(
    const float* __restrict__ W0, const float* __restrict__ W1,
    const float* __restrict__ W2, const float* __restrict__ W3,
    const float* __restrict__ W4, const float* __restrict__ W5,
    f16* __restrict__ Wt)
{
  int z = blockIdx.y;
  const float* W = z==0?W0 : z==1?W1 : z==2?W2 : z==3?W3 : z==4?W4 : W5;
  f16* T = Wt + (size_t)z * WSZP;
  int id = blockIdx.x * 256 + threadIdx.x;    // [0, 49152) 16B units
  int col = id & 127;
  int t = id >> 7;
  int g = t & 1; t >>= 1;
  int tap = t % 3; t /= 3;
  int p = t & 1; t >>= 1;
  int s = t & 15;
  int bn = t >> 4;
  int chan = s * 16 + g * 8;
  int colg = bn * 128 + col;
  f16x8 o;
  #pragma unroll
  for (int e = 0; e < 8; ++e) {
    float w = W[(size_t)(tap * 256 + chan + e) * 256 + colg];
    f16 h = (f16)w;
    o[e] = p ? (f16)(w - (float)h) : h;
  }
  *(f16x8*)(T + (size_t)id * 8) = o;
}

// ---------------- split f32 -> hi/lo planes (Xq layout) ----------------
__global__ __launch_bounds__(256) void split2(
    const float* __restrict__ X, f16* __restrict__ Hi, f16* __restrict__ Lo)
{
  int id = blockIdx.x * 256 + threadIdx.x;    // [0, MM*32)
  int row = id >> 5, pane = id & 31;
  const float* src = X + (size_t)row * 256 + pane * 8;
  float4 v0 = *(const float4*)src;
  float4 v1 = *(const float4*)(src + 4);
  float vv[8] = {v0.x, v0.y, v0.z, v0.w, v1.x, v1.y, v1.z, v1.w};
  f16x8 h, l;
  #pragma unroll
  for (int j = 0; j < 8; ++j) {
    f16 hh = (f16)vv[j];
    h[j] = hh;
    l[j] = (f16)(vv[j] - (float)hh);
  }
  size_t o = xoff8(pane, row);
  *(f16x8*)(Hi + o) = h;
  *(f16x8*)(Lo + o) = l;
}

// Row-kernel lane mapping: wave covers 2 rows; lane -> (rowoff = lane>>5,
// pane = lane&31), each lane handles 8 chans (16B) -> fully coalesced.
// Reductions use __shfl_xor over 16..1 (stay within 32-lane halves).

// ---------------- fused LN (z picks predictor set) ----------------
__global__ __launch_bounds__(256) void lnF(
    f16* __restrict__ P0h, f16* __restrict__ P0l,
    f16* __restrict__ P1h, f16* __restrict__ P1l,
    const float* __restrict__ g0, const float* __restrict__ be0,
    const float* __restrict__ g1, const float* __restrict__ be1)
{
  int z = blockIdx.y;
  f16* Ph = z ? P1h : P0h;
  f16* Pl = z ? P1l : P0l;
  const float* g  = z ? g1 : g0;
  const float* be = z ? be1 : be0;
  int tid = threadIdx.x, lane = tid & 63;
  int row  = blockIdx.x * 8 + (tid >> 6) * 2 + (lane >> 5);
  int pane = lane & 31;
  size_t o = xoff8(pane, row);
  f16x8 h = *(const f16x8*)(Ph + o);
  f16x8 l = *(const f16x8*)(Pl + o);
  float v[8];
  #pragma unroll
  for (int j = 0; j < 8; ++j) v[j] = (float)h[j] + (float)l[j];
  float s = 0.f, q = 0.f;
  #pragma unroll
  for (int j = 0; j < 8; ++j) { s += v[j]; q += v[j] * v[j]; }
  #pragma unroll
  for (int d = 16; d > 0; d >>= 1) { s += __shfl_xor(s, d); q += __shfl_xor(q, d); }
  float mean = s * (1.f / 256.f);
  float var  = q * (1.f / 256.f) - mean * mean;
  float inv  = 1.0f / sqrtf(var + 1e-5f);
  float4 ga = *(const float4*)(g + pane * 8);
  float4 gb = *(const float4*)(g + pane * 8 + 4);
  float4 ba = *(const float4*)(be + pane * 8);
  float4 bb = *(const float4*)(be + pane * 8 + 4);
  float gv[8] = {ga.x, ga.y, ga.z, ga.w, gb.x, gb.y, gb.z, gb.w};
  float bv[8] = {ba.x, ba.y, ba.z, ba.w, bb.x, bb.y, bb.z, bb.w};
  #pragma unroll
  for (int j = 0; j < 8; ++j) {
    float oo = (v[j] - mean) * inv * gv[j] + bv[j];
    f16 hh = (f16)oo;
    h[j] = hh;
    l[j] = (f16)(oo - (float)hh);
  }
  *(f16x8*)(Ph + o) = h;
  *(f16x8*)(Pl + o) = l;
}

// ------- fused LN+head for dur (z=0) and pit (z=1, + bucket + emb add) -------
__global__ __launch_bounds__(256) void lnheadD(
    const f16* __restrict__ U0h, const f16* __restrict__ U0l,
    const f16* __restrict__ U1h, const f16* __restrict__ U1l,
    const float* __restrict__ g0, const float* __restrict__ be0,
    const float* __restrict__ wl0, const float* __restrict__ bl0,
    const float* __restrict__ g1, const float* __restrict__ be1,
    const float* __restrict__ wl1, const float* __restrict__ bl1,
    const unsigned char* __restrict__ mask, const float* __restrict__ pc,
    float* __restrict__ o_ldur, float* __restrict__ pred_d,
    float* __restrict__ o_pit,
    const float* __restrict__ pbins, const float* __restrict__ pemb,
    const f16* __restrict__ XPh, const f16* __restrict__ XPl,
    f16* __restrict__ X1h, f16* __restrict__ X1l)
{
  int z = blockIdx.y;
  int tid = threadIdx.x, lane = tid & 63;
  int row  = blockIdx.x * 8 + (tid >> 6) * 2 + (lane >> 5);
  int pane = lane & 31;
  size_t o = xoff8(pane, row);
  const f16* Uh = z ? U1h : U0h;
  const f16* Ul = z ? U1l : U0l;
  f16x8 h = *(const f16x8*)(Uh + o);
  f16x8 l = *(const f16x8*)(Ul + o);
  float v[8];
  #pragma unroll
  for (int j = 0; j < 8; ++j) v[j] = (float)h[j] + (float)l[j];
  float s = 0.f, q = 0.f;
  #pragma unroll
  for (int j = 0; j < 8; ++j) { s += v[j]; q += v[j] * v[j]; }
  #pragma unroll
  for (int d = 16; d > 0; d >>= 1) { s += __shfl_xor(s, d); q += __shfl_xor(q, d); }
  float mean = s * (1.f / 256.f);
  float var  = q * (1.f / 256.f) - mean * mean;
  float inv  = 1.0f / sqrtf(var + 1e-5f);
  const float* g  = z ? g1  : g0;
  const float* be = z ? be1 : be0;
  const float* wl = z ? wl1 : wl0;
  float4 ga = *(const float4*)(g + pane * 8);
  float4 gb = *(const float4*)(g + pane * 8 + 4);
  float4 ba = *(const float4*)(be + pane * 8);
  float4 bb = *(const float4*)(be + pane * 8 + 4);
  float4 wa = *(const float4*)(wl + pane * 8);
  float4 wb = *(const float4*)(wl + pane * 8 + 4);
  float gv[8] = {ga.x, ga.y, ga.z, ga.w, gb.x, gb.y, gb.z, gb.w};
  float bv[8] = {ba.x, ba.y, ba.z, ba.w, bb.x, bb.y, bb.z, bb.w};
  float wv[8] = {wa.x, wa.y, wa.z, wa.w, wb.x, wb.y, wb.z, wb.w};
  float acc = 0.f;
  #pragma unroll
  for (int j = 0; j < 8; ++j)
    acc += ((v[j] - mean) * inv * gv[j] + bv[j]) * wv[j];
  #pragma unroll
  for (int d = 16; d > 0; d >>= 1) acc += __shfl_xor(acc, d);
  float r = acc + (z ? bl1 : bl0)[0];
  if (mask[row]) r = 0.f;
  if (z == 0) {
    if (pane == 0) { o_ldur[row] = r; pred_d[row] = r; }
  } else {
    r *= pc[0];
    if (pane == 0) o_pit[row] = r;
    int lo = 0, hi = 255;
    while (lo < hi) { int mid = (lo + hi) >> 1; if (pbins[mid] < r) lo = mid + 1; else hi = mid; }
    f16x8 xh = *(const f16x8*)(XPh + o);
    f16x8 xl = *(const f16x8*)(XPl + o);
    float4 ea = *(const float4*)(pemb + (size_t)lo * HH + pane * 8);
    float4 eb = *(const float4*)(pemb + (size_t)lo * HH + pane * 8 + 4);
    float ev[8] = {ea.x, ea.y, ea.z, ea.w, eb.x, eb.y, eb.z, eb.w};
    #pragma unroll
    for (int j = 0; j < 8; ++j) {
      float oo = (float)xh[j] + (float)xl[j] + ev[j];
      f16 hh = (f16)oo;
      xh[j] = hh;
      xl[j] = (f16)(oo - (float)hh);
    }
    *(f16x8*)(X1h + o) = xh;
    *(f16x8*)(X1l + o) = xl;
  }
}

// ------- energy: sum split-K partials + bias + relu + LN -> planes -------
__global__ __launch_bounds__(256) void lnS(
    const float* __restrict__ C0, const float* __restrict__ C1,
    const float* __restrict__ bias,
    const float* __restrict__ g, const float* __restrict__ be,
    f16* __restrict__ Yh, f16* __restrict__ Yl)
{
  int tid = threadIdx.x, lane = tid & 63;
  int row  = blockIdx.x * 8 + (tid >> 6) * 2 + (lane >> 5);
  int pane = lane & 31;
  size_t ci = (size_t)row * 256 + pane * 8;
  float4 a0 = *(const float4*)(C0 + ci);
  float4 a1 = *(const float4*)(C0 + ci + 4);
  float4 b0 = *(const float4*)(C1 + ci);
  float4 b1 = *(const float4*)(C1 + ci + 4);
  float4 s0 = *(const float4*)(bias + pane * 8);
  float4 s1 = *(const float4*)(bias + pane * 8 + 4);
  float v[8] = {fmaxf(a0.x + b0.x + s0.x, 0.f), fmaxf(a0.y + b0.y + s0.y, 0.f),
                fmaxf(a0.z + b0.z + s0.z, 0.f), fmaxf(a0.w + b0.w + s0.w, 0.f),
                fmaxf(a1.x + b1.x + s1.x, 0.f), fmaxf(a1.y + b1.y + s1.y, 0.f),
                fmaxf(a1.z + b1.z + s1.z, 0.f), fmaxf(a1.w + b1.w + s1.w, 0.f)};
  float s = 0.f, q = 0.f;
  #pragma unroll
  for (int j = 0; j < 8; ++j) { s += v[j]; q += v[j] * v[j]; }
  #pragma unroll
  for (int d = 16; d > 0; d >>= 1) { s += __shfl_xor(s, d); q += __shfl_xor(q, d); }
  float mean = s * (1.f / 256.f);
  float var  = q * (1.f / 256.f) - mean * mean;
  float inv  = 1.0f / sqrtf(var + 1e-5f);
  float4 ga = *(const float4*)(g + pane * 8);
  float4 gb = *(const float4*)(g + pane * 8 + 4);
  float4 ba = *(const float4*)(be + pane * 8);
  float4 bb = *(const float4*)(be + pane * 8 + 4);
  float gv[8] = {ga.x, ga.y, ga.z, ga.w, gb.x, gb.y, gb.z, gb.w};
  float bv[8] = {ba.x, ba.y, ba.z, ba.w, bb.x, bb.y, bb.z, bb.w};
  f16x8 h, l;
  #pragma unroll
  for (int j = 0; j < 8; ++j) {
    float oo = (v[j] - mean) * inv * gv[j] + bv[j];
    f16 hh = (f16)oo;
    h[j] = hh;
    l[j] = (f16)(oo - (float)hh);
  }
  size_t o = xoff8(pane, row);
  *(f16x8*)(Yh + o) = h;
  *(f16x8*)(Yl + o) = l;
}

// ------- energy final: sum partials + bias + relu + LN + head + bucket -------
__global__ __launch_bounds__(256) void lnheadS(
    const float* __restrict__ C0, const float* __restrict__ C1,
    const float* __restrict__ bias,
    const float* __restrict__ g, const float* __restrict__ be,
    const float* __restrict__ wl, const float* __restrict__ bl,
    const unsigned char* __restrict__ mask, const float* __restrict__ ec,
    float* __restrict__ o_ene,
    const float* __restrict__ ebins, const float* __restrict__ eemb,
    const f16* __restrict__ X1h, const f16* __restrict__ X1l,
    f16* __restrict__ X2h, f16* __restrict__ X2l)
{
  int tid = threadIdx.x, lane = tid & 63;
  int row  = blockIdx.x * 8 + (tid >> 6) * 2 + (lane >> 5);
  int pane = lane & 31;
  size_t ci = (size_t)row * 256 + pane * 8;
  float4 a0 = *(const float4*)(C0 + ci);
  float4 a1 = *(const float4*)(C0 + ci + 4);
  float4 b0 = *(const float4*)(C1 + ci);
  float4 b1 = *(const float4*)(C1 + ci + 4);
  float4 s0 = *(const float4*)(bias + pane * 8);
  float4 s1 = *(const float4*)(bias + pane * 8 + 4);
  float v[8] = {fmaxf(a0.x + b0.x + s0.x, 0.f), fmaxf(a0.y + b0.y + s0.y, 0.f),
                fmaxf(a0.z + b0.z + s0.z, 0.f), fmaxf(a0.w + b0.w + s0.w, 0.f),
                fmaxf(a1.x + b1.x + s1.x, 0.f), fmaxf(a1.y + b1.y + s1.y, 0.f),
                fmaxf(a1.z + b1.z + s1.z, 0.f), fmaxf(a1.w + b1.w + s1.w, 0.f)};
  float s = 0.f, q = 0.f;
  #pragma unroll
  for (int j = 0; j < 8; ++j) { s += v[j]; q += v[j] * v[j]; }
  #pragma unroll
  for (int d = 16; d > 0; d >>= 1) { s += __shfl_xor(s, d); q += __shfl_xor(q, d); }
  float mean = s * (1.f / 256.f);
  float var  = q * (1.f / 256.f) - mean * mean;
  float inv  = 1.0f / sqrtf(var + 1e-5f);
  float4 ga = *(const float4*)(g + pane * 8);
  float4 gb = *(const float4*)(g + pane * 8 + 4);
  float4 ba = *(const float4*)(be + pane * 8);
  float4 bb = *(const float4*)(be + pane * 8 + 4);
  float4 wa = *(const float4*)(wl + pane * 8);
  float4 wb = *(const float4*)(wl + pane * 8 + 4);
  float gv[8] = {ga.x, ga.y, ga.z, ga.w, gb.x, gb.y, gb.z, gb.w};
  float bv[8] = {ba.x, ba.y, ba.z, ba.w, bb.x, bb.y, bb.z, bb.w};
  float wv[8] = {wa.x, wa.y, wa.z, wa.w, wb.x, wb.y, wb.z, wb.w};
  float acc = 0.f;
  #pragma unroll
  for (int j = 0; j < 8; ++j)
    acc += ((v[j] - mean) * inv * gv[j] + bv[j]) * wv[j];
  #pragma unroll
  for (int d = 16; d > 0; d >>= 1) acc += __shfl_xor(acc, d);
  float r = acc + bl[0];
  if (mask[row]) r = 0.f;
  r *= ec[0];
  if (pane == 0) o_ene[row] = r;
  int lo = 0, hi = 255;
  while (lo < hi) { int mid = (lo + hi) >> 1; if (ebins[mid] < r) lo = mid + 1; else hi = mid; }
  size_t o = xoff8(pane, row);
  f16x8 xh = *(const f16x8*)(X1h + o);
  f16x8 xl = *(const f16x8*)(X1l + o);
  float4 ea = *(const float4*)(eemb + (size_t)lo * HH + pane * 8);
  float4 eb = *(const float4*)(eemb + (size_t)lo * HH + pane * 8 + 4);
  float ev[8] = {ea.x, ea.y, ea.z, ea.w, eb.x, eb.y, eb.z, eb.w};
  #pragma unroll
  for (int j = 0; j < 8; ++j) {
    float oo = (float)xh[j] + (float)xl[j] + ev[j];
    f16 hh = (f16)oo;
    xh[j] = hh;
    xl[j] = (f16)(oo - (float)hh);
  }
  *(f16x8*)(X2h + o) = xh;
  *(f16x8*)(X2l + o) = xl;
}

// ---------------- duration post: dur, cumsum, mel_len ----------------
__global__ __launch_bounds__(512) void dur_post(
    const float* __restrict__ logdur, const float* __restrict__ dc,
    float* __restrict__ out_dur, float* __restrict__ out_mel_len,
    int* __restrict__ cum_ws, int* __restrict__ mel_len_ws)
{
  __shared__ int wsum[8];
  int b = blockIdx.x, t = threadIdx.x;
  float ld = logdur[b * SS + t];
  float d  = fmaxf(rintf(expf(ld) - 1.f) * dc[0], 0.f);
  out_dur[b * SS + t] = d;
  int di = (int)d;
  int lane = t & 63, w = t >> 6;
  int x = di;
  #pragma unroll
  for (int dd = 1; dd < 64; dd <<= 1) {
    int n = __shfl_up(x, dd);
    if (lane >= dd) x += n;
  }
  if (lane == 63) wsum[w] = x;
  __syncthreads();
  int off = 0;
  for (int i = 0; i < w; ++i) off += wsum[i];
  x += off;
  cum_ws[b * SS + t] = x;
  if (t == SS - 1) {
    int ml = min(x, MAXMEL);
    mel_len_ws[b] = ml;
    out_mel_len[b] = (float)ml;
  }
}

// ---------------- length regulator from Xq planes ----------------
__global__ __launch_bounds__(256) void gather_planes(
    const f16* __restrict__ Xhi, const f16* __restrict__ Xlo,
    const int* __restrict__ cum, const int* __restrict__ mel_len_ws,
    float* __restrict__ out_x, float* __restrict__ out_mask)
{
  __shared__ int c[SS];
  int b   = blockIdx.y;
  int tid = threadIdx.x;
  c[tid]       = cum[b * SS + tid];
  c[tid + 256] = cum[b * SS + tid + 256];
  __syncthreads();
  int lane = tid & 63, w = tid >> 6;
  int t = blockIdx.x * 8 + w * 2 + (lane >> 5);
  int pane = lane & 31;
  int lo = 0, hi = SS;
  while (lo < hi) { int mid = (lo + hi) >> 1; if (c[mid] <= t) lo = mid + 1; else hi = mid; }
  int idx = min(lo, SS - 1);
  int ml  = mel_len_ws[b];
  bool m  = (t >= ml);
  float v[8] = {0.f, 0.f, 0.f, 0.f, 0.f, 0.f, 0.f, 0.f};
  if (!m) {
    size_t o = xoff8(pane, b * SS + idx);
    f16x8 xh = *(const f16x8*)(Xhi + o);
    f16x8 xl = *(const f16x8*)(Xlo + o);
    #pragma unroll
    for (int j = 0; j < 8; ++j) v[j] = (float)xh[j] + (float)xl[j];
  }
  float* dst = out_x + ((size_t)b * MAXMEL + t) * HH + pane * 8;
  *(float4*)dst       = make_float4(v[0], v[1], v[2], v[3]);
  *(float4*)(dst + 4) = make_float4(v[4], v[5], v[6], v[7]);
  if (pane == 0) out_mask[b * MAXMEL + t] = m ? 1.f : 0.f;
}

// ---------------- launcher ----------------
extern "C" void kernel_launch(void* const* d_in, const int* in_sizes, int n_in,
                              void* d_out, int out_size, void* d_ws, size_t ws_size,
                              hipStream_t stream) {
  const float* x     = (const float*)d_in[0];
  const unsigned char* smask = (const unsigned char*)d_in[1];
  const float* pc    = (const float*)d_in[2];
  const float* ec    = (const float*)d_in[3];
  const float* dc    = (const float*)d_in[4];
  const float* pbins = (const float*)d_in[5];
  const float* ebins = (const float*)d_in[6];
  const float* pemb  = (const float*)d_in[7];
  const float* eemb  = (const float*)d_in[8];

  float* out = (float*)d_out;
  float* o_xexp  = out;
  float* o_pit   = out + (size_t)16777216;
  float* o_ene   = o_pit + 16384;
  float* o_ldur  = o_ene + 16384;
  float* o_dur   = o_ldur + 16384;
  float* o_mlen  = o_dur + 16384;
  float* o_mmask = o_mlen + 32;

  const size_t PL = (size_t)MM * HH;       // f16 elems per plane
  f16* p = (f16*)d_ws;
  f16 *XPh = p,        *XPl = p + PL;
  f16 *Tdh = p + 2*PL, *Tdl = p + 3*PL;
  f16 *Tph = p + 4*PL, *Tpl = p + 5*PL;
  f16 *Udh = p + 6*PL, *Udl = p + 7*PL;
  f16 *Uph = p + 8*PL, *Upl = p + 9*PL;
  f16 *X1h = p + 10*PL, *X1l = p + 11*PL;
  f16 *Teh = p + 12*PL, *Tel = p + 13*PL;
  f16 *X2h = p + 14*PL, *X2l = p + 15*PL;
  f16* Wt  = p + 16*PL;                    // 6 packed convs of WSZP
  float* C0 = (float*)(Wt + 6 * WSZP);     // 2 x MM*256 f32
  float* C1 = C0 + (size_t)MM * 256;
  float* pred_d = C1 + (size_t)MM * 256;
  int*   cum = (int*)(pred_d + MM);
  int*   mlw = cum + MM;

  #define WPK(i) (Wt + (size_t)(i) * WSZP)

  // weights: 0=dur w1(9), 1=dur w2(13), 2=pit w1(19), 3=pit w2(23), 4=ene w1(29), 5=ene w2(33)
  wsplit6<<<dim3(192, 6), 256, 0, stream>>>(
      (const float*)d_in[9], (const float*)d_in[13], (const float*)d_in[19],
      (const float*)d_in[23], (const float*)d_in[29], (const float*)d_in[33], Wt);

  split2<<<2048, 256, 0, stream>>>(x, XPh, XPl);

  dim3 cgrid(128, 2, 2);
  dim3 rgrid8(MM / 8);
  dim3 rgrid8x2(MM / 8, 2);

  // fused dur+pit conv1
  conv16<16, 0><<<cgrid, 256, 0, stream>>>(
      XPh, XPl, XPh, XPl, WPK(0), WPK(2),
      (const float*)d_in[10], (const float*)d_in[20],
      Tdh, Tdl, Tph, Tpl, nullptr);
  lnF<<<rgrid8x2, 256, 0, stream>>>(Tdh, Tdl, Tph, Tpl,
      (const float*)d_in[11], (const float*)d_in[12],
      (const float*)d_in[21], (const float*)d_in[22]);
  // fused dur+pit conv2
  conv16<16, 0><<<cgrid, 256, 0, stream>>>(
      Tdh, Tdl, Tph, Tpl, WPK(1), WPK(3),
      (const float*)d_in[14], (const float*)d_in[24],
      Udh, Udl, Uph, Upl, nullptr);
  lnheadD<<<rgrid8x2, 256, 0, stream>>>(
      Udh, Udl, Uph, Upl,
      (const float*)d_in[15], (const float*)d_in[16],
      (const float*)d_in[17], (const float*)d_in[18],
      (const float*)d_in[25], (const float*)d_in[26],
      (const float*)d_in[27], (const float*)d_in[28],
      smask, pc, o_ldur, pred_d, o_pit, pbins, pemb,
      XPh, XPl, X1h, X1l);
  dur_post<<<BB, 512, 0, stream>>>(pred_d, dc, o_dur, o_mlen, cum, mlw);

  // energy conv1 (split-K over bz) -> raw C
  conv16<8, 1><<<cgrid, 256, 0, stream>>>(
      X1h, X1l, X1h, X1l, WPK(4), WPK(4),
      nullptr, nullptr, nullptr, nullptr, nullptr, nullptr, C0);
  lnS<<<rgrid8, 256, 0, stream>>>(C0, C1, (const float*)d_in[30],
      (const float*)d_in[31], (const float*)d_in[32], Teh, Tel);
  // energy conv2 (split-K) -> raw C
  conv16<8, 1><<<cgrid, 256, 0, stream>>>(
      Teh, Tel, Teh, Tel, WPK(5), WPK(5),
      nullptr, nullptr, nullptr, nullptr, nullptr, nullptr, C0);
  lnheadS<<<rgrid8, 256, 0, stream>>>(C0, C1, (const float*)d_in[34],
      (const float*)d_in[35], (const float*)d_in[36],
      (const float*)d_in[37], (const float*)d_in[38],
      smask, ec, o_ene, ebins, eemb, X1h, X1l, X2h, X2l);

  dim3 ggrid(MAXMEL / 8, BB);
  gather_planes<<<ggrid, 256, 0, stream>>>(X2h, X2l, cum, mlw, o_xexp, o_mmask);

  #undef WPK
}

// Round 10
// 228.457 us; speedup vs baseline: 1.0197x; 1.0197x over previous
//
#include <hip/hip_runtime.h>
#include <stdint.h>

#define BB 32
#define SS 512
#define HH 256
#define MM (BB*SS)     // 16384 rows
#define MAXMEL 2048

typedef _Float16 f16;
typedef _Float16 f16x4 __attribute__((ext_vector_type(4)));
typedef _Float16 f16x8 __attribute__((ext_vector_type(8)));
typedef float    f32x16 __attribute__((ext_vector_type(16)));

#define BAR()  asm volatile("s_barrier" ::: "memory")
#define VMW9() asm volatile("s_waitcnt vmcnt(9)" ::: "memory")
#define VMW8() asm volatile("s_waitcnt vmcnt(8)" ::: "memory")
#define VMW7() asm volatile("s_waitcnt vmcnt(7)" ::: "memory")
#define VMW0() asm volatile("s_waitcnt vmcnt(0)" ::: "memory")

// Xq layout: [pane 32][row MM][8 f16], pane = chan>>3. 16B per row per pane.
__device__ __forceinline__ size_t xoff8(int pane, int row) {
  return ((size_t)pane * MM + row) * 8;
}

#define WSZP ((size_t)393216)   // packed weight f16 elems per conv (both planes)

// ================= conv256: N=256 block, fused LN (+head) epilogue ==========
// Block 128 rows x 256 cols, 512 thr (8 waves 2wr x 4wc), wave 64x64 as 2x2
// frags of 32x32x16. 16 steps of 16 chans x 3 taps, dbuf LDS, counted vmcnt.
// 3-product split: Ahi*Bhi + Ahi*Blo + Alo*Bhi (~f32).
// LDS: B0 @0 (49152 = [p2][tap3][g2][col256][16B]), B1 @49152,
//      A0 @98304 (12288 = [p2][g2][lr192][16B] + 64B zero), A1 @110656.
// Epilogue scratch (reuses B region): PS@0, MEANS@4096, DP@5120, BKT@7168.
#define CBSTR 49152
#define CAOFF 98304
#define CABUF 12352
#define CAZ   110592
#define CLDS  123008
#define PSOFF 0
#define MNOFF 4096
#define DPOFF 5120
#define BKOFF 7168

template<int MODE>   // 0: LN -> planes; 1: LN+head (bz0: dur scalars, bz1: pit+bucket+emb)
__global__ __launch_bounds__(512) void conv256(
    const f16* __restrict__ X0h, const f16* __restrict__ X0l,
    const f16* __restrict__ X1h_, const f16* __restrict__ X1l_,
    const f16* __restrict__ W0, const f16* __restrict__ W1,
    const float* __restrict__ bias0, const float* __restrict__ bias1,
    const float* __restrict__ g0, const float* __restrict__ be0,
    const float* __restrict__ g1, const float* __restrict__ be1,
    f16* __restrict__ Y0h, f16* __restrict__ Y0l,
    f16* __restrict__ Y1h, f16* __restrict__ Y1l,
    const float* __restrict__ wl0, const float* __restrict__ bl0,
    const float* __restrict__ wl1, const float* __restrict__ bl1,
    const unsigned char* __restrict__ mask, const float* __restrict__ pc,
    float* __restrict__ o_ldur, float* __restrict__ pred_d,
    float* __restrict__ o_pit,
    const float* __restrict__ pbins, const float* __restrict__ pemb,
    const f16* __restrict__ XPh, const f16* __restrict__ XPl,
    f16* __restrict__ XO1h, f16* __restrict__ XO1l)
{
  __shared__ __align__(16) unsigned char smem[CLDS];
  const int tid = threadIdx.x;
  const int lane = tid & 63, wid = tid >> 6;
  const int bm = blockIdx.x, bz = blockIdx.z;
  const int l31 = lane & 31, half = lane >> 5;
  const int wr = wid >> 2, wc = wid & 3;

  const f16* Xh = bz ? X1h_ : X0h;
  const f16* Xl = bz ? X1l_ : X0l;
  const f16* Wp = bz ? W1 : W0;

  // ---- stage descriptors: 60 DMAs/block-step; waves 0-3: 8, waves 4-7: 7 ----
  const f16* sb[8]; int sdst[8]; int sdb[8]; size_t sstr[8];
  #pragma unroll
  for (int i = 0; i < 8; ++i) {
    int j = (wid < 4) ? (wid * 8 + i) : (32 + (wid - 4) * 7 + i);
    if (j > 59) j = 32;                 // dup (never issued)
    if (j < 12) {                       // A: [p2][g2][3 segs of 64 rows]
      int p = j / 6, rem = j % 6, g = rem / 3, seg = rem % 3;
      int lr = seg * 64 + lane;
      int row = bm * 128 - 32 + lr;
      row = row < 0 ? 0 : (row >= MM ? MM - 1 : row);
      sb[i]   = (p ? Xl : Xh) + ((size_t)g * MM + row) * 8;
      sstr[i] = (size_t)MM * 16;
      sdst[i] = CAOFF + p * 6144 + g * 3072 + lr * 16;
      sdb[i]  = CABUF;
    } else {                            // B: [p2][tap3][g2][4 x 64 cols]
      int jj = j - 12;                  // 0..47
      int p = jj / 24, rest = jj % 24;
      int tap = rest >> 3, rem = rest & 7;
      int g = rem >> 2, q4 = rem & 3;
      sb[i]   = Wp + ((((size_t)(p * 3 + tap) * 2 + g) * 256) + q4 * 64 + lane) * 8;
      sstr[i] = 24576;
      sdst[i] = p * 24576 + tap * 8192 + g * 4096 + q4 * 1024 + lane * 16;
      sdb[i]  = CBSTR;
    }
  }

  // ---- fragment read addresses (lane-contiguous) ----
  int a_addr[3][2][2];            // [tap][mi][p]
  #pragma unroll
  for (int tap = 0; tap < 3; ++tap)
    #pragma unroll
    for (int mi = 0; mi < 2; ++mi) {
      int row_l = wr * 64 + mi * 32 + l31;
      int sseq = (bm & 3) * 128 + row_l + tap - 1;
      bool valid = (unsigned)sseq < 512u;
      int lr = row_l + tap + 31;
      #pragma unroll
      for (int p = 0; p < 2; ++p)
        a_addr[tap][mi][p] = valid ? (CAOFF + p * 6144 + half * 3072 + lr * 16)
                                   : CAZ;
    }
  int b_base[2];
  #pragma unroll
  for (int n = 0; n < 2; ++n)
    b_base[n] = half * 4096 + (wc * 64 + n * 32 + l31) * 16;

  f32x16 acc[2][2];
  #pragma unroll
  for (int mi = 0; mi < 2; ++mi)
    #pragma unroll
    for (int ni = 0; ni < 2; ++ni) acc[mi][ni] = (f32x16)0.f;

  auto STAGE = [&](int buf, int step) {
    #pragma unroll
    for (int i = 0; i < 7; ++i)
      __builtin_amdgcn_global_load_lds(
        (const __attribute__((address_space(1))) void*)(sb[i] + (size_t)step * sstr[i]),
        (__attribute__((address_space(3))) void*)(smem + sdst[i] + buf * sdb[i]),
        16, 0, 0);
    if (wid < 4)
      __builtin_amdgcn_global_load_lds(
        (const __attribute__((address_space(1))) void*)(sb[7] + (size_t)step * sstr[7]),
        (__attribute__((address_space(3))) void*)(smem + sdst[7] + buf * sdb[7]),
        16, 0, 0);
  };

  auto COMP = [&](int buf) {
    #pragma unroll
    for (int tap = 0; tap < 3; ++tap) {
      f16x8 av[2][2], bv[2][2];        // [p][mi], [p][ni]
      #pragma unroll
      for (int p = 0; p < 2; ++p)
        #pragma unroll
        for (int q = 0; q < 2; ++q) {
          av[p][q] = *(const f16x8*)(smem + (a_addr[tap][q][p] + buf * CABUF));
          bv[p][q] = *(const f16x8*)(smem + (buf * CBSTR + p * 24576 + tap * 8192 + b_base[q]));
        }
      #pragma unroll
      for (int mi = 0; mi < 2; ++mi)
        #pragma unroll
        for (int ni = 0; ni < 2; ++ni) {
          acc[mi][ni] = __builtin_amdgcn_mfma_f32_32x32x16_f16(av[0][mi], bv[0][ni], acc[mi][ni], 0, 0, 0);
          acc[mi][ni] = __builtin_amdgcn_mfma_f32_32x32x16_f16(av[0][mi], bv[1][ni], acc[mi][ni], 0, 0, 0);
          acc[mi][ni] = __builtin_amdgcn_mfma_f32_32x32x16_f16(av[1][mi], bv[0][ni], acc[mi][ni], 0, 0, 0);
        }
    }
  };

  if (tid < 4) {
    *(float4*)(smem + CAZ + tid * 16) = make_float4(0.f, 0.f, 0.f, 0.f);
    *(float4*)(smem + CAZ + CABUF + tid * 16) = make_float4(0.f, 0.f, 0.f, 0.f);
  }
  STAGE(0, 0); STAGE(1, 1);
  __syncthreads();

  #pragma unroll
  for (int i = 0; i < 16; ++i) {
    COMP(i & 1);
    BAR();
    if (i < 14)       { STAGE(i & 1, i + 2); if (wid < 4) VMW8(); else VMW7(); }
    else if (i == 14) { VMW0(); }
    BAR();
  }

  // ================= fused epilogue =================
  const float* bias = bz ? bias1 : bias0;
  const float* gam  = bz ? g1 : g0;
  const float* bet  = bz ? be1 : be0;
  const int colg0 = wc * 64 + l31;
  const int colg1 = colg0 + 32;
  const float bq0 = bias[colg0], bq1 = bias[colg1];

  // phase 1: per-row sum / sumsq of relu(acc+bias)
  #pragma unroll
  for (int mi = 0; mi < 2; ++mi)
    #pragma unroll
    for (int r = 0; r < 16; ++r) {
      float v0 = fmaxf(acc[mi][0][r] + bq0, 0.f);
      float v1 = fmaxf(acc[mi][1][r] + bq1, 0.f);
      float s = v0 + v1, q = v0 * v0 + v1 * v1;
      #pragma unroll
      for (int d = 16; d > 0; d >>= 1) { s += __shfl_xor(s, d); q += __shfl_xor(q, d); }
      if (l31 == 0) {
        int row_l = wr * 64 + mi * 32 + (r & 3) + 8 * (r >> 2) + 4 * half;
        *(float2*)(smem + PSOFF + (row_l * 4 + wc) * 8) = make_float2(s, q);
      }
    }
  BAR();
  if (tid < 128) {
    int row = tid;
    float s = 0.f, q = 0.f;
    #pragma unroll
    for (int w = 0; w < 4; ++w) {
      float2 pq = *(float2*)(smem + PSOFF + (row * 4 + w) * 8);
      s += pq.x; q += pq.y;
    }
    float mean = s * (1.f / 256.f);
    float var  = q * (1.f / 256.f) - mean * mean;
    float inv  = 1.0f / sqrtf(var + 1e-5f);
    *(float2*)(smem + MNOFF + row * 8) = make_float2(mean, inv);
  }
  BAR();

  const float gv0 = gam[colg0], gv1 = gam[colg1];
  const float bv0 = bet[colg0], bv1 = bet[colg1];
  size_t cb0 = (size_t)(colg0 >> 3) * MM * 8 + (colg0 & 7);
  size_t cb1 = (size_t)(colg1 >> 3) * MM * 8 + (colg1 & 7);

  if constexpr (MODE == 0) {
    f16* Yh = bz ? Y1h : Y0h;
    f16* Yl = bz ? Y1l : Y0l;
    #pragma unroll
    for (int mi = 0; mi < 2; ++mi)
      #pragma unroll
      for (int r = 0; r < 16; ++r) {
        int row_l = wr * 64 + mi * 32 + (r & 3) + 8 * (r >> 2) + 4 * half;
        int rowg = bm * 128 + row_l;
        float2 m2 = *(float2*)(smem + MNOFF + row_l * 8);
        float v0 = fmaxf(acc[mi][0][r] + bq0, 0.f);
        float v1 = fmaxf(acc[mi][1][r] + bq1, 0.f);
        float o0 = (v0 - m2.x) * m2.y * gv0 + bv0;
        float o1 = (v1 - m2.x) * m2.y * gv1 + bv1;
        f16 h0 = (f16)o0, h1 = (f16)o1;
        size_t p0 = cb0 + (size_t)rowg * 8, p1 = cb1 + (size_t)rowg * 8;
        Yh[p0] = h0; Yl[p0] = (f16)(o0 - (float)h0);
        Yh[p1] = h1; Yl[p1] = (f16)(o1 - (float)h1);
      }
  } else {
    const float* wl = bz ? wl1 : wl0;
    const float wv0 = wl[colg0], wv1 = wl[colg1];
    // phase 2: per-row dot(ln(v), wl)
    #pragma unroll
    for (int mi = 0; mi < 2; ++mi)
      #pragma unroll
      for (int r = 0; r < 16; ++r) {
        int row_l = wr * 64 + mi * 32 + (r & 3) + 8 * (r >> 2) + 4 * half;
        float2 m2 = *(float2*)(smem + MNOFF + row_l * 8);
        float v0 = fmaxf(acc[mi][0][r] + bq0, 0.f);
        float v1 = fmaxf(acc[mi][1][r] + bq1, 0.f);
        float dp = ((v0 - m2.x) * m2.y * gv0 + bv0) * wv0
                 + ((v1 - m2.x) * m2.y * gv1 + bv1) * wv1;
        #pragma unroll
        for (int d = 16; d > 0; d >>= 1) dp += __shfl_xor(dp, d);
        if (l31 == 0)
          *(float*)(smem + DPOFF + (row_l * 4 + wc) * 4) = dp;
      }
    BAR();
    if (tid < 128) {
      int row = tid, rowg = bm * 128 + row;
      float hd = (bz ? bl1 : bl0)[0];
      #pragma unroll
      for (int w = 0; w < 4; ++w) hd += *(float*)(smem + DPOFF + (row * 4 + w) * 4);
      if (mask[rowg]) hd = 0.f;
      if (bz == 0) {
        o_ldur[rowg] = hd;
        pred_d[rowg] = hd;
      } else {
        hd *= pc[0];
        o_pit[rowg] = hd;
        int lo = 0, hi = 255;
        while (lo < hi) { int mid = (lo + hi) >> 1; if (pbins[mid] < hd) lo = mid + 1; else hi = mid; }
        *(int*)(smem + BKOFF + row * 4) = lo;
      }
    }
    if (bz == 1) {           // bucket + emb add -> X1 planes
      BAR();
      #pragma unroll
      for (int mi = 0; mi < 2; ++mi)
        #pragma unroll
        for (int r = 0; r < 16; ++r) {
          int row_l = wr * 64 + mi * 32 + (r & 3) + 8 * (r >> 2) + 4 * half;
          int rowg = bm * 128 + row_l;
          int bkt = *(int*)(smem + BKOFF + row_l * 4);
          float e0 = pemb[(size_t)bkt * HH + colg0];
          float e1 = pemb[(size_t)bkt * HH + colg1];
          size_t p0 = cb0 + (size_t)rowg * 8, p1 = cb1 + (size_t)rowg * 8;
          float x0 = (float)XPh[p0] + (float)XPl[p0] + e0;
          float x1 = (float)XPh[p1] + (float)XPl[p1] + e1;
          f16 h0 = (f16)x0, h1 = (f16)x1;
          XO1h[p0] = h0; XO1l[p0] = (f16)(x0 - (float)h0);
          XO1h[p1] = h1; XO1l[p1] = (f16)(x1 - (float)h1);
        }
    }
  }
}

// ================= convKS: energy split-K (raw f32 partials) ================
// Round-9 structure: N=128 (bn grid), bz = K-half (8 steps), dbuf, vmcnt(9).
#define KAOFF  49152
#define KABUF  12352
#define KAZ    61440
#define KBBUF  24576
#define KLDS   73856

__global__ __launch_bounds__(256) void convKS(
    const f16* __restrict__ Xh, const f16* __restrict__ Xl,
    const f16* __restrict__ Wp,
    float* __restrict__ Craw)
{
  __shared__ __align__(16) unsigned char smem[KLDS];
  const int tid = threadIdx.x;
  const int lane = tid & 63, wid = tid >> 6;
  const int bm = blockIdx.x, bn = blockIdx.y, bz = blockIdx.z;
  const int l31 = lane & 31, half = lane >> 5;
  const int wr = wid >> 1, wc = wid & 1;
  const int s0 = bz * 8;

  const f16* sb[9]; int sdst[9]; int sdb[9]; size_t sstr[9];
  #pragma unroll
  for (int i = 0; i < 9; ++i) {
    int j = wid * 9 + i;
    if (j < 12) {
      int p = j / 6, rem = j % 6, g = rem / 3, seg = rem % 3;
      int lr = seg * 64 + lane;
      int row = bm * 128 - 32 + lr;
      row = row < 0 ? 0 : (row >= MM ? MM - 1 : row);
      sb[i]   = (p ? Xl : Xh) + ((size_t)g * MM + row) * 8;
      sstr[i] = (size_t)MM * 16;
      sdst[i] = KAOFF + p * 6144 + g * 3072 + lr * 16;
      sdb[i]  = KABUF;
    } else {
      int jj = j - 12;
      int p = jj / 12, rest = jj % 12;
      int tap = rest >> 2, q = rest & 3;
      int g = q >> 1, h2 = q & 1;
      sb[i]   = Wp + ((((size_t)(p * 3 + tap) * 2 + g) * 256) + bn * 128 + h2 * 64 + lane) * 8;
      sstr[i] = 24576;
      sdst[i] = p * 12288 + tap * 4096 + g * 2048 + h2 * 1024 + lane * 16;
      sdb[i]  = KBBUF;
    }
  }

  int a_addr[3][2][2];
  #pragma unroll
  for (int tap = 0; tap < 3; ++tap)
    #pragma unroll
    for (int mi = 0; mi < 2; ++mi) {
      int row_l = wr * 64 + mi * 32 + l31;
      int sseq = (bm & 3) * 128 + row_l + tap - 1;
      bool valid = (unsigned)sseq < 512u;
      int lr = row_l + tap + 31;
      #pragma unroll
      for (int p = 0; p < 2; ++p)
        a_addr[tap][mi][p] = valid ? (KAOFF + p * 6144 + half * 3072 + lr * 16) : KAZ;
    }
  int b_base[2];
  #pragma unroll
  for (int n = 0; n < 2; ++n)
    b_base[n] = half * 2048 + (wc * 64 + n * 32 + l31) * 16;

  f32x16 acc[2][2];
  #pragma unroll
  for (int mi = 0; mi < 2; ++mi)
    #pragma unroll
    for (int ni = 0; ni < 2; ++ni) acc[mi][ni] = (f32x16)0.f;

  auto STAGE = [&](int buf, int step) {
    #pragma unroll
    for (int i = 0; i < 9; ++i)
      __builtin_amdgcn_global_load_lds(
        (const __attribute__((address_space(1))) void*)(sb[i] + (size_t)step * sstr[i]),
        (__attribute__((address_space(3))) void*)(smem + sdst[i] + buf * sdb[i]),
        16, 0, 0);
  };

  auto COMP = [&](int buf) {
    #pragma unroll
    for (int tap = 0; tap < 3; ++tap) {
      f16x8 av[2][2], bv[2][2];
      #pragma unroll
      for (int p = 0; p < 2; ++p)
        #pragma unroll
        for (int q = 0; q < 2; ++q) {
          av[p][q] = *(const f16x8*)(smem + (a_addr[tap][q][p] + buf * KABUF));
          bv[p][q] = *(const f16x8*)(smem + (buf * KBBUF + p * 12288 + tap * 4096 + b_base[q]));
        }
      #pragma unroll
      for (int mi = 0; mi < 2; ++mi)
        #pragma unroll
        for (int ni = 0; ni < 2; ++ni) {
          acc[mi][ni] = __builtin_amdgcn_mfma_f32_32x32x16_f16(av[0][mi], bv[0][ni], acc[mi][ni], 0, 0, 0);
          acc[mi][ni] = __builtin_amdgcn_mfma_f32_32x32x16_f16(av[0][mi], bv[1][ni], acc[mi][ni], 0, 0, 0);
          acc[mi][ni] = __builtin_amdgcn_mfma_f32_32x32x16_f16(av[1][mi], bv[0][ni], acc[mi][ni], 0, 0, 0);
        }
    }
  };

  if (tid < 4) {
    *(float4*)(smem + KAZ + tid * 16) = make_float4(0.f, 0.f, 0.f, 0.f);
    *(float4*)(smem + KAZ + KABUF + tid * 16) = make_float4(0.f, 0.f, 0.f, 0.f);
  }
  STAGE(0, s0); STAGE(1, s0 + 1);
  __syncthreads();

  #pragma unroll
  for (int i = 0; i < 8; ++i) {
    COMP(i & 1);
    BAR();
    if (i < 6)       { STAGE(i & 1, s0 + i + 2); VMW9(); }
    else if (i == 6) { VMW0(); }
    BAR();
  }

  float* C = Craw + (size_t)bz * MM * 256;
  #pragma unroll
  for (int mi = 0; mi < 2; ++mi)
    #pragma unroll
    for (int ni = 0; ni < 2; ++ni) {
      int colg = bn * 128 + wc * 64 + ni * 32 + l31;
      #pragma unroll
      for (int r = 0; r < 16; ++r) {
        int rowl = (r & 3) + 8 * (r >> 2) + 4 * half;
        size_t rowg = (size_t)bm * 128 + wr * 64 + mi * 32 + rowl;
        C[rowg * 256 + colg] = acc[mi][ni][r];
      }
    }
}

// ---------------- weight pack+split, all 6 weights in one launch ----------------
// packed per conv, 16B unit id = ((((s*2+p)*3+tap)*2+g)*256 + col
__global__ __launch_bounds__(256) void wsplit6(
    const float* __restrict__ W0, const float* __restrict__ W1,
    const float* __restrict__ W2, const float* __restrict__ W3,
    const float* __restrict__ W4, const float* __restrict__ W5,
    f16* __restrict__ Wt)
{
  int z = blockIdx.y;
  const float* W = z==0?W0 : z==1?W1 : z==2?W2 : z==3?W3 : z==4?W4 : W5;
  f16* T = Wt + (size_t)z * WSZP;
  int id = blockIdx.x * 256 + threadIdx.x;    // [0, 49152) 16B units
  int col = id & 255;
  int t = id >> 8;
  int g = t & 1; t >>= 1;
  int tap = t % 3; t /= 3;
  int p = t & 1; t >>= 1;
  int s = t;
  int chan = s * 16 + g * 8;
  f16x8 o;
  #pragma unroll
  for (int e = 0; e < 8; ++e) {
    float w = W[(size_t)(tap * 256 + chan + e) * 256 + col];
    f16 h = (f16)w;
    o[e] = p ? (f16)(w - (float)h) : h;
  }
  *(f16x8*)(T + (size_t)id * 8) = o;
}

// ---------------- split f32 -> hi/lo planes (Xq layout) ----------------
__global__ __launch_bounds__(256) void split2(
    const float* __restrict__ X, f16* __restrict__ Hi, f16* __restrict__ Lo)
{
  int id = blockIdx.x * 256 + threadIdx.x;    // [0, MM*32)
  int row = id >> 5, pane = id & 31;
  const float* src = X + (size_t)row * 256 + pane * 8;
  float4 v0 = *(const float4*)src;
  float4 v1 = *(const float4*)(src + 4);
  float vv[8] = {v0.x, v0.y, v0.z, v0.w, v1.x, v1.y, v1.z, v1.w};
  f16x8 h, l;
  #pragma unroll
  for (int j = 0; j < 8; ++j) {
    f16 hh = (f16)vv[j];
    h[j] = hh;
    l[j] = (f16)(vv[j] - (float)hh);
  }
  size_t o = xoff8(pane, row);
  *(f16x8*)(Hi + o) = h;
  *(f16x8*)(Lo + o) = l;
}

// ------- energy: sum split-K partials + bias + relu + LN -> planes -------
__global__ __launch_bounds__(256) void lnS(
    const float* __restrict__ C0, const float* __restrict__ C1,
    const float* __restrict__ bias,
    const float* __restrict__ g, const float* __restrict__ be,
    f16* __restrict__ Yh, f16* __restrict__ Yl)
{
  int tid = threadIdx.x, lane = tid & 63;
  int row  = blockIdx.x * 8 + (tid >> 6) * 2 + (lane >> 5);
  int pane = lane & 31;
  size_t ci = (size_t)row * 256 + pane * 8;
  float4 a0 = *(const float4*)(C0 + ci);
  float4 a1 = *(const float4*)(C0 + ci + 4);
  float4 b0 = *(const float4*)(C1 + ci);
  float4 b1 = *(const float4*)(C1 + ci + 4);
  float4 s0 = *(const float4*)(bias + pane * 8);
  float4 s1 = *(const float4*)(bias + pane * 8 + 4);
  float v[8] = {fmaxf(a0.x + b0.x + s0.x, 0.f), fmaxf(a0.y + b0.y + s0.y, 0.f),
                fmaxf(a0.z + b0.z + s0.z, 0.f), fmaxf(a0.w + b0.w + s0.w, 0.f),
                fmaxf(a1.x + b1.x + s1.x, 0.f), fmaxf(a1.y + b1.y + s1.y, 0.f),
                fmaxf(a1.z + b1.z + s1.z, 0.f), fmaxf(a1.w + b1.w + s1.w, 0.f)};
  float s = 0.f, q = 0.f;
  #pragma unroll
  for (int j = 0; j < 8; ++j) { s += v[j]; q += v[j] * v[j]; }
  #pragma unroll
  for (int d = 16; d > 0; d >>= 1) { s += __shfl_xor(s, d); q += __shfl_xor(q, d); }
  float mean = s * (1.f / 256.f);
  float var  = q * (1.f / 256.f) - mean * mean;
  float inv  = 1.0f / sqrtf(var + 1e-5f);
  float4 ga = *(const float4*)(g + pane * 8);
  float4 gb = *(const float4*)(g + pane * 8 + 4);
  float4 ba = *(const float4*)(be + pane * 8);
  float4 bb = *(const float4*)(be + pane * 8 + 4);
  float gv[8] = {ga.x, ga.y, ga.z, ga.w, gb.x, gb.y, gb.z, gb.w};
  float bv[8] = {ba.x, ba.y, ba.z, ba.w, bb.x, bb.y, bb.z, bb.w};
  f16x8 h, l;
  #pragma unroll
  for (int j = 0; j < 8; ++j) {
    float oo = (v[j] - mean) * inv * gv[j] + bv[j];
    f16 hh = (f16)oo;
    h[j] = hh;
    l[j] = (f16)(oo - (float)hh);
  }
  size_t o = xoff8(pane, row);
  *(f16x8*)(Yh + o) = h;
  *(f16x8*)(Yl + o) = l;
}

// ------- energy final: sum partials + bias + relu + LN + head + bucket -------
__global__ __launch_bounds__(256) void lnheadS(
    const float* __restrict__ C0, const float* __restrict__ C1,
    const float* __restrict__ bias,
    const float* __restrict__ g, const float* __restrict__ be,
    const float* __restrict__ wl, const float* __restrict__ bl,
    const unsigned char* __restrict__ mask, const float* __restrict__ ec,
    float* __restrict__ o_ene,
    const float* __restrict__ ebins, const float* __restrict__ eemb,
    const f16* __restrict__ X1h, const f16* __restrict__ X1l,
    f16* __restrict__ X2h, f16* __restrict__ X2l)
{
  int tid = threadIdx.x, lane = tid & 63;
  int row  = blockIdx.x * 8 + (tid >> 6) * 2 + (lane >> 5);
  int pane = lane & 31;
  size_t ci = (size_t)row * 256 + pane * 8;
  float4 a0 = *(const float4*)(C0 + ci);
  float4 a1 = *(const float4*)(C0 + ci + 4);
  float4 b0 = *(const float4*)(C1 + ci);
  float4 b1 = *(const float4*)(C1 + ci + 4);
  float4 s0 = *(const float4*)(bias + pane * 8);
  float4 s1 = *(const float4*)(bias + pane * 8 + 4);
  float v[8] = {fmaxf(a0.x + b0.x + s0.x, 0.f), fmaxf(a0.y + b0.y + s0.y, 0.f),
                fmaxf(a0.z + b0.z + s0.z, 0.f), fmaxf(a0.w + b0.w + s0.w, 0.f),
                fmaxf(a1.x + b1.x + s1.x, 0.f), fmaxf(a1.y + b1.y + s1.y, 0.f),
                fmaxf(a1.z + b1.z + s1.z, 0.f), fmaxf(a1.w + b1.w + s1.w, 0.f)};
  float s = 0.f, q = 0.f;
  #pragma unroll
  for (int j = 0; j < 8; ++j) { s += v[j]; q += v[j] * v[j]; }
  #pragma unroll
  for (int d = 16; d > 0; d >>= 1) { s += __shfl_xor(s, d); q += __shfl_xor(q, d); }
  float mean = s * (1.f / 256.f);
  float var  = q * (1.f / 256.f) - mean * mean;
  float inv  = 1.0f / sqrtf(var + 1e-5f);
  float4 ga = *(const float4*)(g + pane * 8);
  float4 gb = *(const float4*)(g + pane * 8 + 4);
  float4 ba = *(const float4*)(be + pane * 8);
  float4 bb = *(const float4*)(be + pane * 8 + 4);
  float4 wa = *(const float4*)(wl + pane * 8);
  float4 wb = *(const float4*)(wl + pane * 8 + 4);
  float gv[8] = {ga.x, ga.y, ga.z, ga.w, gb.x, gb.y, gb.z, gb.w};
  float bv[8] = {ba.x, ba.y, ba.z, ba.w, bb.x, bb.y, bb.z, bb.w};
  float wv[8] = {wa.x, wa.y, wa.z, wa.w, wb.x, wb.y, wb.z, wb.w};
  float acc = 0.f;
  #pragma unroll
  for (int j = 0; j < 8; ++j)
    acc += ((v[j] - mean) * inv * gv[j] + bv[j]) * wv[j];
  #pragma unroll
  for (int d = 16; d > 0; d >>= 1) acc += __shfl_xor(acc, d);
  float r = acc + bl[0];
  if (mask[row]) r = 0.f;
  r *= ec[0];
  if (pane == 0) o_ene[row] = r;
  int lo = 0, hi = 255;
  while (lo < hi) { int mid = (lo + hi) >> 1; if (ebins[mid] < r) lo = mid + 1; else hi = mid; }
  size_t o = xoff8(pane, row);
  f16x8 xh = *(const f16x8*)(X1h + o);
  f16x8 xl = *(const f16x8*)(X1l + o);
  float4 ea = *(const float4*)(eemb + (size_t)lo * HH + pane * 8);
  float4 eb = *(const float4*)(eemb + (size_t)lo * HH + pane * 8 + 4);
  float ev[8] = {ea.x, ea.y, ea.z, ea.w, eb.x, eb.y, eb.z, eb.w};
  #pragma unroll
  for (int j = 0; j < 8; ++j) {
    float oo = (float)xh[j] + (float)xl[j] + ev[j];
    f16 hh = (f16)oo;
    xh[j] = hh;
    xl[j] = (f16)(oo - (float)hh);
  }
  *(f16x8*)(X2h + o) = xh;
  *(f16x8*)(X2l + o) = xl;
}

// ---------------- duration post: dur, cumsum, mel_len ----------------
__global__ __launch_bounds__(512) void dur_post(
    const float* __restrict__ logdur, const float* __restrict__ dc,
    float* __restrict__ out_dur, float* __restrict__ out_mel_len,
    int* __restrict__ cum_ws, int* __restrict__ mel_len_ws)
{
  __shared__ int wsum[8];
  int b = blockIdx.x, t = threadIdx.x;
  float ld = logdur[b * SS + t];
  float d  = fmaxf(rintf(expf(ld) - 1.f) * dc[0], 0.f);
  out_dur[b * SS + t] = d;
  int di = (int)d;
  int lane = t & 63, w = t >> 6;
  int x = di;
  #pragma unroll
  for (int dd = 1; dd < 64; dd <<= 1) {
    int n = __shfl_up(x, dd);
    if (lane >= dd) x += n;
  }
  if (lane == 63) wsum[w] = x;
  __syncthreads();
  int off = 0;
  for (int i = 0; i < w; ++i) off += wsum[i];
  x += off;
  cum_ws[b * SS + t] = x;
  if (t == SS - 1) {
    int ml = min(x, MAXMEL);
    mel_len_ws[b] = ml;
    out_mel_len[b] = (float)ml;
  }
}

// ---------------- length regulator from Xq planes ----------------
__global__ __launch_bounds__(256) void gather_planes(
    const f16* __restrict__ Xhi, const f16* __restrict__ Xlo,
    const int* __restrict__ cum, const int* __restrict__ mel_len_ws,
    float* __restrict__ out_x, float* __restrict__ out_mask)
{
  __shared__ int c[SS];
  int b   = blockIdx.y;
  int tid = threadIdx.x;
  c[tid]       = cum[b * SS + tid];
  c[tid + 256] = cum[b * SS + tid + 256];
  __syncthreads();
  int lane = tid & 63, w = tid >> 6;
  int t = blockIdx.x * 8 + w * 2 + (lane >> 5);
  int pane = lane & 31;
  int lo = 0, hi = SS;
  while (lo < hi) { int mid = (lo + hi) >> 1; if (c[mid] <= t) lo = mid + 1; else hi = mid; }
  int idx = min(lo, SS - 1);
  int ml  = mel_len_ws[b];
  bool m  = (t >= ml);
  float v[8] = {0.f, 0.f, 0.f, 0.f, 0.f, 0.f, 0.f, 0.f};
  if (!m) {
    size_t o = xoff8(pane, b * SS + idx);
    f16x8 xh = *(const f16x8*)(Xhi + o);
    f16x8 xl = *(const f16x8*)(Xlo + o);
    #pragma unroll
    for (int j = 0; j < 8; ++j) v[j] = (float)xh[j] + (float)xl[j];
  }
  float* dst = out_x + ((size_t)b * MAXMEL + t) * HH + pane * 8;
  *(float4*)dst       = make_float4(v[0], v[1], v[2], v[3]);
  *(float4*)(dst + 4) = make_float4(v[4], v[5], v[6], v[7]);
  if (pane == 0) out_mask[b * MAXMEL + t] = m ? 1.f : 0.f;
}

// ---------------- launcher ----------------
extern "C" void kernel_launch(void* const* d_in, const int* in_sizes, int n_in,
                              void* d_out, int out_size, void* d_ws, size_t ws_size,
                              hipStream_t stream) {
  const float* x     = (const float*)d_in[0];
  const unsigned char* smask = (const unsigned char*)d_in[1];
  const float* pc    = (const float*)d_in[2];
  const float* ec    = (const float*)d_in[3];
  const float* dc    = (const float*)d_in[4];
  const float* pbins = (const float*)d_in[5];
  const float* ebins = (const float*)d_in[6];
  const float* pemb  = (const float*)d_in[7];
  const float* eemb  = (const float*)d_in[8];

  float* out = (float*)d_out;
  float* o_xexp  = out;
  float* o_pit   = out + (size_t)16777216;
  float* o_ene   = o_pit + 16384;
  float* o_ldur  = o_ene + 16384;
  float* o_dur   = o_ldur + 16384;
  float* o_mlen  = o_dur + 16384;
  float* o_mmask = o_mlen + 32;

  const size_t PL = (size_t)MM * HH;       // f16 elems per plane
  f16* p = (f16*)d_ws;
  f16 *XPh = p,        *XPl = p + PL;
  f16 *Tdh = p + 2*PL, *Tdl = p + 3*PL;
  f16 *Tph = p + 4*PL, *Tpl = p + 5*PL;
  f16 *X1h = p + 6*PL, *X1l = p + 7*PL;
  f16 *Teh = p + 8*PL, *Tel = p + 9*PL;
  f16 *X2h = p + 10*PL, *X2l = p + 11*PL;
  f16* Wt  = p + 12*PL;                    // 6 packed convs of WSZP
  float* C0 = (float*)(Wt + 6 * WSZP);     // 2 x MM*256 f32
  float* C1 = C0 + (size_t)MM * 256;
  float* pred_d = C1 + (size_t)MM * 256;
  int*   cum = (int*)(pred_d + MM);
  int*   mlw = cum + MM;

  #define WPK(i) (Wt + (size_t)(i) * WSZP)

  // weights: 0=dur w1(9), 1=dur w2(13), 2=pit w1(19), 3=pit w2(23), 4=ene w1(29), 5=ene w2(33)
  wsplit6<<<dim3(192, 6), 256, 0, stream>>>(
      (const float*)d_in[9], (const float*)d_in[13], (const float*)d_in[19],
      (const float*)d_in[23], (const float*)d_in[29], (const float*)d_in[33], Wt);

  split2<<<2048, 256, 0, stream>>>(x, XPh, XPl);

  dim3 cgrid256(128, 1, 2);
  dim3 kgrid(128, 2, 2);
  dim3 rgrid8(MM / 8);

  // fused dur+pit conv1 + LN
  conv256<0><<<cgrid256, 512, 0, stream>>>(
      XPh, XPl, XPh, XPl, WPK(0), WPK(2),
      (const float*)d_in[10], (const float*)d_in[20],
      (const float*)d_in[11], (const float*)d_in[12],
      (const float*)d_in[21], (const float*)d_in[22],
      Tdh, Tdl, Tph, Tpl,
      nullptr, nullptr, nullptr, nullptr,
      nullptr, nullptr, nullptr, nullptr, nullptr,
      nullptr, nullptr, nullptr, nullptr, nullptr, nullptr);
  // fused dur+pit conv2 + LN + head (+ pit bucket/emb -> X1)
  conv256<1><<<cgrid256, 512, 0, stream>>>(
      Tdh, Tdl, Tph, Tpl, WPK(1), WPK(3),
      (const float*)d_in[14], (const float*)d_in[24],
      (const float*)d_in[15], (const float*)d_in[16],
      (const float*)d_in[25], (const float*)d_in[26],
      nullptr, nullptr, nullptr, nullptr,
      (const float*)d_in[17], (const float*)d_in[18],
      (const float*)d_in[27], (const float*)d_in[28],
      smask, pc, o_ldur, pred_d, o_pit, pbins, pemb,
      XPh, XPl, X1h, X1l);
  dur_post<<<BB, 512, 0, stream>>>(pred_d, dc, o_dur, o_mlen, cum, mlw);

  // energy conv1 (split-K over bz) -> raw C
  convKS<<<kgrid, 256, 0, stream>>>(X1h, X1l, WPK(4), C0);
  lnS<<<rgrid8, 256, 0, stream>>>(C0, C1, (const float*)d_in[30],
      (const float*)d_in[31], (const float*)d_in[32], Teh, Tel);
  // energy conv2 (split-K) -> raw C
  convKS<<<kgrid, 256, 0, stream>>>(Teh, Tel, WPK(5), C0);
  lnheadS<<<rgrid8, 256, 0, stream>>>(C0, C1, (const float*)d_in[34],
      (const float*)d_in[35], (const float*)d_in[36],
      (const float*)d_in[37], (const float*)d_in[38],
      smask, ec, o_ene, ebins, eemb, X1h, X1l, X2h, X2l);

  dim3 ggrid(MAXMEL / 8, BB);
  gather_planes<<<ggrid, 256, 0, stream>>>(X2h, X2l, cum, mlw, o_xexp, o_mmask);

  #undef WPK
}